// Round 1
// baseline (273.786 us; speedup 1.0000x reference)
//
#include <hip/hip_runtime.h>
#include <math.h>

#define N_NODES 50000
#define D_IN    128
#define E_EDGES 800000
#define H_HEADS 8
#define F_FEAT  32
#define T_TYPES 8
#define HF      256
#define NEG_SLOPE 0.2f

// ---------------------------------------------------------------------------
// Kernel 1: histogram of edge types
// ---------------------------------------------------------------------------
__global__ __launch_bounds__(256) void hist_kernel(const int* __restrict__ etype,
                                                   int* __restrict__ counts) {
    __shared__ int sh[T_TYPES];
    if (threadIdx.x < T_TYPES) sh[threadIdx.x] = 0;
    __syncthreads();
    int stride = gridDim.x * blockDim.x;
    for (int e = blockIdx.x * blockDim.x + threadIdx.x; e < E_EDGES; e += stride)
        atomicAdd(&sh[etype[e]], 1);
    __syncthreads();
    if (threadIdx.x < T_TYPES) atomicAdd(&counts[threadIdx.x], sh[threadIdx.x]);
}

// ---------------------------------------------------------------------------
// Kernel 2: small precomputed tables
//   M[h][j]    = sum_f attn_e[h,f] * W_e[h*32+f, j]          (8x8)
//   ttab[t][h] = sum_f attn_et[h,f] * sum_f2 W_et[h*32+f,f2]*type_emb[t,f2]
//   w[t]       = E / (T * counts[t])
// ---------------------------------------------------------------------------
__global__ void tables_kernel(const float* __restrict__ attn_e,
                              const float* __restrict__ W_e,
                              const float* __restrict__ attn_et,
                              const float* __restrict__ W_et,
                              const float* __restrict__ type_emb,
                              const int* __restrict__ counts,
                              float* __restrict__ M, float* __restrict__ ttab,
                              float* __restrict__ w) {
    int t = threadIdx.x;          // 0..63
    int h = t >> 3, j = t & 7;    // j doubles as edge-type index
    float m = 0.f;
    for (int f = 0; f < F_FEAT; ++f)
        m += attn_e[h * 32 + f] * W_e[(h * 32 + f) * 8 + j];
    M[h * 8 + j] = m;
    float tt = 0.f;
    for (int f = 0; f < F_FEAT; ++f) {
        float inner = 0.f;
        for (int f2 = 0; f2 < F_FEAT; ++f2)
            inner += W_et[(h * 32 + f) * 32 + f2] * type_emb[j * 32 + f2];
        tt += attn_et[h * 32 + f] * inner;
    }
    ttab[j * 8 + h] = tt;         // [type][head]
    if (t < T_TYPES) {
        int c = counts[t]; if (c < 1) c = 1;
        w[t] = (float)E_EDGES / (8.0f * (float)c);
    }
}

// ---------------------------------------------------------------------------
// Kernel 3: node transform  fs = feat @ W_src^T   (+ fused el, er)
//   W staged transposed in LDS [k][c] (stride 260 for aligned b128 reads);
//   16 nodes per block-iteration, 4 nodes per wave, 4 cols per lane.
// ---------------------------------------------------------------------------
__global__ __launch_bounds__(256) void node_gemm(const float* __restrict__ feat,
                                                 const float* __restrict__ W,
                                                 const float* __restrict__ attn_l,
                                                 const float* __restrict__ attn_r,
                                                 float* __restrict__ fs,
                                                 float* __restrict__ el,
                                                 float* __restrict__ er) {
    __shared__ float Wt[D_IN][260];  // Wt[k][c] = W[c][k]
    __shared__ float ft[D_IN][20];   // ft[k][j], j = node-in-group (16 + pad)
    const int t = threadIdx.x;
    // stage W transposed (one-time per block)
    for (int i = 0; i < (HF * D_IN) / 256; ++i) {
        int idx = i * 256 + t;
        int r = idx >> 7;        // output column c
        int k = idx & 127;       // input dim k
        Wt[k][r] = W[idx];
    }
    const int wid = t >> 6;          // wave 0..3
    const int l = t & 63;            // lane
    const int c0 = 4 * l;            // this lane's 4 columns
    const int jb = 4 * wid;          // this wave's 4 nodes in the group
    const float4 al = *(const float4*)&attn_l[c0];
    const float4 ar = *(const float4*)&attn_r[c0];

    const int ngroups = (N_NODES + 15) / 16;
    for (int g = blockIdx.x; g < ngroups; g += gridDim.x) {
        const int nbase = g * 16;
        __syncthreads();             // protect ft reuse + cover W stage 1st iter
        for (int i = 0; i < (16 * D_IN) / 256; ++i) {
            int idx = i * 256 + t;
            int j = idx >> 7;        // node in group
            int k = idx & 127;
            int n = nbase + j;
            ft[k][j] = (n < N_NODES) ? feat[n * D_IN + k] : 0.f;
        }
        __syncthreads();

        float a00=0,a01=0,a02=0,a03=0, a10=0,a11=0,a12=0,a13=0;
        float a20=0,a21=0,a22=0,a23=0, a30=0,a31=0,a32=0,a33=0;
#pragma unroll 4
        for (int k = 0; k < D_IN; ++k) {
            float4 wv = *(const float4*)&Wt[k][c0];
            float4 fv = *(const float4*)&ft[k][jb];
            a00 += fv.x*wv.x; a01 += fv.x*wv.y; a02 += fv.x*wv.z; a03 += fv.x*wv.w;
            a10 += fv.y*wv.x; a11 += fv.y*wv.y; a12 += fv.y*wv.z; a13 += fv.y*wv.w;
            a20 += fv.z*wv.x; a21 += fv.z*wv.y; a22 += fv.z*wv.z; a23 += fv.z*wv.w;
            a30 += fv.w*wv.x; a31 += fv.w*wv.y; a32 += fv.w*wv.z; a33 += fv.w*wv.w;
        }
        float accs[4][4] = {{a00,a01,a02,a03},{a10,a11,a12,a13},
                            {a20,a21,a22,a23},{a30,a31,a32,a33}};
#pragma unroll
        for (int j = 0; j < 4; ++j) {
            int n = nbase + jb + j;   // wave-uniform
            float pl = accs[j][0]*al.x + accs[j][1]*al.y + accs[j][2]*al.z + accs[j][3]*al.w;
            float pr = accs[j][0]*ar.x + accs[j][1]*ar.y + accs[j][2]*ar.z + accs[j][3]*ar.w;
            // reduce within 8-lane groups (lanes sharing a head)
            pl += __shfl_xor(pl, 1); pr += __shfl_xor(pr, 1);
            pl += __shfl_xor(pl, 2); pr += __shfl_xor(pr, 2);
            pl += __shfl_xor(pl, 4); pr += __shfl_xor(pr, 4);
            if (n < N_NODES) {
                *(float4*)&fs[n * HF + c0] =
                    make_float4(accs[j][0], accs[j][1], accs[j][2], accs[j][3]);
                if ((l & 7) == 0) {
                    int h = l >> 3;
                    el[n * 8 + h] = pl;
                    er[n * 8 + h] = pr;
                }
            }
        }
    }
}

// ---------------------------------------------------------------------------
// Kernel 4: CSR row offsets from sorted dst (binary search per node)
// ---------------------------------------------------------------------------
__global__ __launch_bounds__(256) void build_offsets(const int* __restrict__ dst,
                                                     int* __restrict__ off) {
    int n = blockIdx.x * blockDim.x + threadIdx.x;
    if (n > N_NODES) return;
    int lo = 0, hi = E_EDGES;
    while (lo < hi) {
        int mid = (lo + hi) >> 1;
        if (dst[mid] < n) lo = mid + 1; else hi = mid;
    }
    off[n] = lo;
}

// ---------------------------------------------------------------------------
// Kernel 5: per-edge attention score (pre-softmax), one thread per edge
// ---------------------------------------------------------------------------
__global__ __launch_bounds__(256) void edge_kernel(const float* __restrict__ ee,
        const int* __restrict__ src, const int* __restrict__ dst,
        const int* __restrict__ etype, const float* __restrict__ el,
        const float* __restrict__ er, const float* __restrict__ M,
        const float* __restrict__ ttab, const float* __restrict__ w,
        float* __restrict__ attn) {
    __shared__ float sM[64], sT[64], sw[8];
    int t = threadIdx.x;
    if (t < 64) { sM[t] = M[t]; sT[t] = ttab[t]; }
    if (t < 8) sw[t] = w[t];
    __syncthreads();
    int e = blockIdx.x * 256 + t;
    if (e >= E_EDGES) return;
    int s = src[e], d = dst[e], ty = etype[e];
    float4 e0 = *(const float4*)&ee[e * 8];
    float4 e1 = *(const float4*)&ee[e * 8 + 4];
    float4 l0 = *(const float4*)&el[s * 8];
    float4 l1 = *(const float4*)&el[s * 8 + 4];
    float4 r0 = *(const float4*)&er[d * 8];
    float4 r1 = *(const float4*)&er[d * 8 + 4];
    float wt = sw[ty];
    float lv[8] = {l0.x,l0.y,l0.z,l0.w,l1.x,l1.y,l1.z,l1.w};
    float rv[8] = {r0.x,r0.y,r0.z,r0.w,r1.x,r1.y,r1.z,r1.w};
    float o[8];
#pragma unroll
    for (int h = 0; h < 8; ++h) {
        float sc = lv[h] + rv[h] + sT[ty * 8 + h];
        sc += e0.x*sM[h*8+0] + e0.y*sM[h*8+1] + e0.z*sM[h*8+2] + e0.w*sM[h*8+3]
            + e1.x*sM[h*8+4] + e1.y*sM[h*8+5] + e1.z*sM[h*8+6] + e1.w*sM[h*8+7];
        sc *= wt;
        o[h] = (sc >= 0.f) ? sc : NEG_SLOPE * sc;
    }
    *(float4*)&attn[e * 8]     = make_float4(o[0], o[1], o[2], o[3]);
    *(float4*)&attn[e * 8 + 4] = make_float4(o[4], o[5], o[6], o[7]);
}

// ---------------------------------------------------------------------------
// Kernel 6: edge softmax + weighted aggregation. One wave per dst node.
// ---------------------------------------------------------------------------
__global__ __launch_bounds__(256) void agg_kernel(const float* __restrict__ attn,
        const float* __restrict__ fs, const int* __restrict__ src,
        const int* __restrict__ off, const float* __restrict__ bias,
        float* __restrict__ out) {
    const int wid = threadIdx.x >> 6;
    const int l = threadIdx.x & 63;
    const int n = blockIdx.x * 4 + wid;
    if (n >= N_NODES) return;
    const int beg = off[n], end = off[n + 1];
    const int f = l & 31;
    const int hb = (l >> 5) * 4;      // this lane's 4 heads: hb..hb+3
    const int ob = n * HF + hb * 32 + f;
    if (beg == end) {                 // no incoming edges -> just bias
        out[ob]      = bias[hb * 32 + f];
        out[ob + 32] = bias[(hb + 1) * 32 + f];
        out[ob + 64] = bias[(hb + 2) * 32 + f];
        out[ob + 96] = bias[(hb + 3) * 32 + f];
        return;
    }
    // passes 1&2: lane layout (sub=l>>3, h=l&7)
    const int h = l & 7, sub = l >> 3;
    float m = -1e30f;
    for (int e = beg + sub; e < end; e += 8) m = fmaxf(m, attn[e * 8 + h]);
    m = fmaxf(m, __shfl_xor(m, 8));
    m = fmaxf(m, __shfl_xor(m, 16));
    m = fmaxf(m, __shfl_xor(m, 32));
    float z = 0.f;
    for (int e = beg + sub; e < end; e += 8) z += __expf(attn[e * 8 + h] - m);
    z += __shfl_xor(z, 8);
    z += __shfl_xor(z, 16);
    z += __shfl_xor(z, 32);
    // redistribute (m, 1/z) for heads hb..hb+3 (head h lives in lane h)
    const float m0 = __shfl(m, hb + 0), m1 = __shfl(m, hb + 1);
    const float m2 = __shfl(m, hb + 2), m3 = __shfl(m, hb + 3);
    const float iz0 = 1.f / __shfl(z, hb + 0), iz1 = 1.f / __shfl(z, hb + 1);
    const float iz2 = 1.f / __shfl(z, hb + 2), iz3 = 1.f / __shfl(z, hb + 3);
    float a0 = 0.f, a1 = 0.f, a2 = 0.f, a3 = 0.f;
    for (int e = beg; e < end; ++e) {
        const int s = src[e];                       // wave-uniform
        const float* fr = fs + (size_t)s * HF;
        const float* ar = attn + (size_t)e * 8;
        const float p0 = __expf(ar[hb + 0] - m0) * iz0;
        const float p1 = __expf(ar[hb + 1] - m1) * iz1;
        const float p2 = __expf(ar[hb + 2] - m2) * iz2;
        const float p3 = __expf(ar[hb + 3] - m3) * iz3;
        a0 += p0 * fr[(hb + 0) * 32 + f];
        a1 += p1 * fr[(hb + 1) * 32 + f];
        a2 += p2 * fr[(hb + 2) * 32 + f];
        a3 += p3 * fr[(hb + 3) * 32 + f];
    }
    out[ob]      = a0 + bias[hb * 32 + f];
    out[ob + 32] = a1 + bias[(hb + 1) * 32 + f];
    out[ob + 64] = a2 + bias[(hb + 2) * 32 + f];
    out[ob + 96] = a3 + bias[(hb + 3) * 32 + f];
}

// ---------------------------------------------------------------------------
extern "C" void kernel_launch(void* const* d_in, const int* in_sizes, int n_in,
                              void* d_out, int out_size, void* d_ws, size_t ws_size,
                              hipStream_t stream) {
    const float* feat     = (const float*)d_in[0];
    const float* ee       = (const float*)d_in[1];
    const int*   src      = (const int*)d_in[2];
    const int*   dst      = (const int*)d_in[3];
    const int*   etype    = (const int*)d_in[4];
    const float* W_src    = (const float*)d_in[5];
    const float* attn_l   = (const float*)d_in[6];
    const float* attn_r   = (const float*)d_in[7];
    const float* attn_e   = (const float*)d_in[8];
    const float* W_e      = (const float*)d_in[9];
    const float* type_emb = (const float*)d_in[10];
    const float* W_et     = (const float*)d_in[11];
    const float* attn_et  = (const float*)d_in[12];
    const float* bias     = (const float*)d_in[13];
    float* out = (float*)d_out;

    char* ws = (char*)d_ws;
    size_t o = 0;
    auto alloc = [&](size_t bytes) -> void* {
        void* p = ws + o;
        o = (o + bytes + 255) & ~(size_t)255;
        return p;
    };
    float* fs    = (float*)alloc((size_t)N_NODES * HF * 4);   // 51.2 MB
    float* el    = (float*)alloc((size_t)N_NODES * 8 * 4);    // 1.6 MB
    float* er    = (float*)alloc((size_t)N_NODES * 8 * 4);    // 1.6 MB
    float* attn  = (float*)alloc((size_t)E_EDGES * 8 * 4);    // 25.6 MB
    int*   off   = (int*)alloc((size_t)(N_NODES + 1) * 4);
    int*   counts= (int*)alloc(T_TYPES * 4);
    float* M     = (float*)alloc(64 * 4);
    float* ttab  = (float*)alloc(64 * 4);
    float* w     = (float*)alloc(T_TYPES * 4);

    hipMemsetAsync(counts, 0, T_TYPES * sizeof(int), stream);
    hist_kernel<<<512, 256, 0, stream>>>(etype, counts);
    tables_kernel<<<1, 64, 0, stream>>>(attn_e, W_e, attn_et, W_et, type_emb,
                                        counts, M, ttab, w);
    node_gemm<<<256, 256, 0, stream>>>(feat, W_src, attn_l, attn_r, fs, el, er);
    build_offsets<<<(N_NODES + 1 + 255) / 256, 256, 0, stream>>>(dst, off);
    edge_kernel<<<(E_EDGES + 255) / 256, 256, 0, stream>>>(
        ee, src, dst, etype, el, er, M, ttab, w, attn);
    agg_kernel<<<(N_NODES + 3) / 4, 256, 0, stream>>>(attn, fs, src, off, bias, out);
}

// Round 2
// 267.169 us; speedup vs baseline: 1.0248x; 1.0248x over previous
//
#include <hip/hip_runtime.h>
#include <math.h>

#define N_NODES 50000
#define D_IN    128
#define E_EDGES 800000
#define H_HEADS 8
#define F_FEAT  32
#define T_TYPES 8
#define HF      256
#define NEG_SLOPE 0.2f

__device__ inline float bf2f(unsigned short u) {
    union { unsigned int i; float f; } v; v.i = ((unsigned int)u) << 16; return v.f;
}
__device__ inline unsigned short f2bf(float f) {
    unsigned int x = __float_as_uint(f);
    unsigned int r = (x + 0x7fffu + ((x >> 16) & 1u)) >> 16;
    return (unsigned short)r;
}

// ---------------------------------------------------------------------------
// Kernel 1: histogram of edge types (register counters + wave reduce)
// ---------------------------------------------------------------------------
__global__ __launch_bounds__(256) void hist_kernel(const int* __restrict__ etype,
                                                   int* __restrict__ counts) {
    int c[8] = {0,0,0,0,0,0,0,0};
    int stride = gridDim.x * blockDim.x;
    for (int e = blockIdx.x * blockDim.x + threadIdx.x; e < E_EDGES; e += stride) {
        int ty = etype[e];
#pragma unroll
        for (int t = 0; t < 8; ++t) c[t] += (ty == t) ? 1 : 0;
    }
#pragma unroll
    for (int t = 0; t < 8; ++t) {
        c[t] += __shfl_xor(c[t], 1);  c[t] += __shfl_xor(c[t], 2);
        c[t] += __shfl_xor(c[t], 4);  c[t] += __shfl_xor(c[t], 8);
        c[t] += __shfl_xor(c[t], 16); c[t] += __shfl_xor(c[t], 32);
    }
    if ((threadIdx.x & 63) == 0) {
#pragma unroll
        for (int t = 0; t < 8; ++t) atomicAdd(&counts[t], c[t]);
    }
}

// ---------------------------------------------------------------------------
// Kernel 2: small precomputed tables (parallelized)
//   M[h][j]    = sum_f attn_e[h,f] * W_e[h*32+f, j]
//   ttab[t][h] = sum_f2 type_emb[t,f2] * q[h,f2],  q[h,f2]=sum_f attn_et*W_et
//   w[t]       = E / (T * counts[t])
// ---------------------------------------------------------------------------
__global__ __launch_bounds__(256) void tables_kernel(const float* __restrict__ attn_e,
                              const float* __restrict__ W_e,
                              const float* __restrict__ attn_et,
                              const float* __restrict__ W_et,
                              const float* __restrict__ type_emb,
                              const int* __restrict__ counts,
                              float* __restrict__ M, float* __restrict__ ttab,
                              float* __restrict__ w) {
    __shared__ float q[8][32];
    int t = threadIdx.x;
    {   // phase 1: q[h][f2], thread = h*32+f2, coalesced W_et reads
        int h = t >> 5, f2 = t & 31;
        float s = 0.f;
#pragma unroll 8
        for (int f = 0; f < F_FEAT; ++f)
            s += attn_et[h * 32 + f] * W_et[(h * 32 + f) * 32 + f2];
        q[h][f2] = s;
    }
    __syncthreads();
    if (t < 64) {
        int h = t >> 3, j = t & 7;
        float m = 0.f;
#pragma unroll 8
        for (int f = 0; f < F_FEAT; ++f)
            m += attn_e[h * 32 + f] * W_e[(h * 32 + f) * 8 + j];
        M[h * 8 + j] = m;
        float tt = 0.f;
#pragma unroll 8
        for (int f2 = 0; f2 < F_FEAT; ++f2)
            tt += type_emb[j * 32 + f2] * q[h][f2];
        ttab[j * 8 + h] = tt;   // [type][head]
    }
    if (t < T_TYPES) {
        int c = counts[t]; if (c < 1) c = 1;
        w[t] = (float)E_EDGES / (8.0f * (float)c);
    }
}

// ---------------------------------------------------------------------------
// Kernel 3: node transform fs = feat @ W_src^T (+ fused el, er), bf16 fs out.
//   Column-split: block parity picks 128 of 256 cols -> 77.8 KB LDS,
//   2 blocks/CU, 2 waves/SIMD. Lane = 2 nodes x 4 cols.
// ---------------------------------------------------------------------------
__global__ __launch_bounds__(256) void node_gemm(const float* __restrict__ feat,
                                                 const float* __restrict__ W,
                                                 const float* __restrict__ attn_l,
                                                 const float* __restrict__ attn_r,
                                                 unsigned short* __restrict__ fsb,
                                                 float* __restrict__ el,
                                                 float* __restrict__ er) {
    __shared__ float Wt[D_IN][132];  // Wt[k][cl] = W[cbase+cl][k], stride 528B (16B-aligned rows)
    __shared__ float ft[D_IN][20];   // ft[k][j], 16 nodes + pad
    const int t = threadIdx.x;
    const int ch = blockIdx.x & 1;   // column half: cols [128*ch, 128*ch+128)
    const int cbase = ch * 128;
    // stage W half, transposed (once per block)
    for (int i = 0; i < 64; ++i) {
        int idx = i * 256 + t;
        int cl = idx >> 7;           // local col 0..127
        int k  = idx & 127;
        Wt[k][cl] = W[(cbase + cl) * D_IN + k];
    }
    const int wid = t >> 6;
    const int l = t & 63;
    const int lc = l & 31;           // column lane 0..31
    const int c0 = 4 * lc;           // local col base
    const int jb = 4 * wid + 2 * (l >> 5);  // this lane's 2 nodes in group
    const float4 al = *(const float4*)&attn_l[cbase + c0];
    const float4 ar = *(const float4*)&attn_r[cbase + c0];
    const int h = lc >> 3;           // local head 0..3 (global = ch*4+h)

    for (int g = blockIdx.x >> 1; g < N_NODES / 16; g += gridDim.x >> 1) {
        const int nbase = g * 16;
        __syncthreads();             // protect ft reuse + cover W stage on 1st iter
        for (int i = 0; i < 8; ++i) {
            int idx = i * 256 + t;
            int j = idx >> 7, k = idx & 127;
            ft[k][j] = feat[(nbase + j) * D_IN + k];
        }
        __syncthreads();

        float acc[2][4];
#pragma unroll
        for (int j = 0; j < 2; ++j)
#pragma unroll
            for (int c = 0; c < 4; ++c) acc[j][c] = 0.f;
#pragma unroll 4
        for (int k = 0; k < D_IN; ++k) {
            float4 wv = *(const float4*)&Wt[k][c0];
            float2 fv = *(const float2*)&ft[k][jb];
            acc[0][0] += fv.x * wv.x; acc[0][1] += fv.x * wv.y;
            acc[0][2] += fv.x * wv.z; acc[0][3] += fv.x * wv.w;
            acc[1][0] += fv.y * wv.x; acc[1][1] += fv.y * wv.y;
            acc[1][2] += fv.y * wv.z; acc[1][3] += fv.y * wv.w;
        }
#pragma unroll
        for (int j = 0; j < 2; ++j) {
            const int n = nbase + jb + j;
            float pl = acc[j][0]*al.x + acc[j][1]*al.y + acc[j][2]*al.z + acc[j][3]*al.w;
            float pr = acc[j][0]*ar.x + acc[j][1]*ar.y + acc[j][2]*ar.z + acc[j][3]*ar.w;
            pl += __shfl_xor(pl, 1); pr += __shfl_xor(pr, 1);
            pl += __shfl_xor(pl, 2); pr += __shfl_xor(pr, 2);
            pl += __shfl_xor(pl, 4); pr += __shfl_xor(pr, 4);
            ushort4 u;
            u.x = f2bf(acc[j][0]); u.y = f2bf(acc[j][1]);
            u.z = f2bf(acc[j][2]); u.w = f2bf(acc[j][3]);
            *(ushort4*)&fsb[(size_t)n * HF + cbase + c0] = u;
            if ((l & 7) == 0) {
                el[n * 8 + ch * 4 + h] = pl;
                er[n * 8 + ch * 4 + h] = pr;
            }
        }
    }
}

// ---------------------------------------------------------------------------
// Kernel 4: CSR row offsets from sorted dst
// ---------------------------------------------------------------------------
__global__ __launch_bounds__(256) void build_offsets(const int* __restrict__ dst,
                                                     int* __restrict__ off) {
    int n = blockIdx.x * blockDim.x + threadIdx.x;
    if (n > N_NODES) return;
    int lo = 0, hi = E_EDGES;
    while (lo < hi) {
        int mid = (lo + hi) >> 1;
        if (dst[mid] < n) lo = mid + 1; else hi = mid;
    }
    off[n] = lo;
}

// ---------------------------------------------------------------------------
// Kernel 5: per-edge p = exp(leakyrelu(w*(el+er+escore+tscore))), bf16 out.
//   No max subtraction needed: logits are O(+-2), exp safe in fp32.
// ---------------------------------------------------------------------------
__global__ __launch_bounds__(256) void edge_kernel(const float* __restrict__ ee,
        const int* __restrict__ src, const int* __restrict__ dst,
        const int* __restrict__ etype, const float* __restrict__ el,
        const float* __restrict__ er, const float* __restrict__ M,
        const float* __restrict__ ttab, const float* __restrict__ w,
        unsigned short* __restrict__ pexp) {
    __shared__ float sM[64], sT[64], sw[8];
    int t = threadIdx.x;
    if (t < 64) { sM[t] = M[t]; sT[t] = ttab[t]; }
    if (t < 8) sw[t] = w[t];
    __syncthreads();
    int e = blockIdx.x * 256 + t;
    if (e >= E_EDGES) return;
    int s = src[e], d = dst[e], ty = etype[e];
    float4 e0 = *(const float4*)&ee[(size_t)e * 8];
    float4 e1 = *(const float4*)&ee[(size_t)e * 8 + 4];
    float4 l0 = *(const float4*)&el[s * 8];
    float4 l1 = *(const float4*)&el[s * 8 + 4];
    float4 r0 = *(const float4*)&er[d * 8];
    float4 r1 = *(const float4*)&er[d * 8 + 4];
    float wt = sw[ty];
    float lv[8] = {l0.x,l0.y,l0.z,l0.w,l1.x,l1.y,l1.z,l1.w};
    float rv[8] = {r0.x,r0.y,r0.z,r0.w,r1.x,r1.y,r1.z,r1.w};
    unsigned int o[4];
#pragma unroll
    for (int hp = 0; hp < 4; ++hp) {
        float p2[2];
#pragma unroll
        for (int i = 0; i < 2; ++i) {
            int h = hp * 2 + i;
            float sc = lv[h] + rv[h] + sT[ty * 8 + h];
            sc += e0.x*sM[h*8+0] + e0.y*sM[h*8+1] + e0.z*sM[h*8+2] + e0.w*sM[h*8+3]
                + e1.x*sM[h*8+4] + e1.y*sM[h*8+5] + e1.z*sM[h*8+6] + e1.w*sM[h*8+7];
            sc *= wt;
            sc = (sc >= 0.f) ? sc : NEG_SLOPE * sc;
            p2[i] = __expf(sc);
        }
        o[hp] = (unsigned int)f2bf(p2[0]) | ((unsigned int)f2bf(p2[1]) << 16);
    }
    *(uint4*)&pexp[(size_t)e * 8] = make_uint4(o[0], o[1], o[2], o[3]);
}

// ---------------------------------------------------------------------------
// Kernel 6: single-pass softmax-normalized aggregation. One wave per dst node.
//   Lane l covers fs-row elements [4l..4l+3] (head h=l>>3); 8B bf16 loads.
// ---------------------------------------------------------------------------
__global__ __launch_bounds__(256) void agg_kernel(const unsigned short* __restrict__ pexp,
        const unsigned short* __restrict__ fsb, const int* __restrict__ src,
        const int* __restrict__ off, const float* __restrict__ bias,
        float* __restrict__ out) {
    const int wid = threadIdx.x >> 6;
    const int l = threadIdx.x & 63;
    const int n = blockIdx.x * 4 + wid;
    if (n >= N_NODES) return;
    const int beg = off[n], end = off[n + 1];
    const int c0 = 4 * l;            // element base in row
    const int h = l >> 3;            // head for these 4 elements
    const float4 b4 = *(const float4*)&bias[c0];
    float* op = &out[(size_t)n * HF + c0];
    if (beg == end) { *(float4*)op = b4; return; }
    float a0 = 0.f, a1 = 0.f, a2 = 0.f, a3 = 0.f, z = 0.f;
    int e = beg;
    for (; e + 1 < end; e += 2) {
        int s0 = src[e], s1 = src[e + 1];
        float p0 = bf2f(pexp[(size_t)e * 8 + h]);
        float p1 = bf2f(pexp[(size_t)(e + 1) * 8 + h]);
        ushort4 f0 = *(const ushort4*)&fsb[(size_t)s0 * HF + c0];
        ushort4 f1 = *(const ushort4*)&fsb[(size_t)s1 * HF + c0];
        a0 += p0 * bf2f(f0.x); a1 += p0 * bf2f(f0.y);
        a2 += p0 * bf2f(f0.z); a3 += p0 * bf2f(f0.w);
        z += p0;
        a0 += p1 * bf2f(f1.x); a1 += p1 * bf2f(f1.y);
        a2 += p1 * bf2f(f1.z); a3 += p1 * bf2f(f1.w);
        z += p1;
    }
    if (e < end) {
        int s0 = src[e];
        float p0 = bf2f(pexp[(size_t)e * 8 + h]);
        ushort4 f0 = *(const ushort4*)&fsb[(size_t)s0 * HF + c0];
        a0 += p0 * bf2f(f0.x); a1 += p0 * bf2f(f0.y);
        a2 += p0 * bf2f(f0.z); a3 += p0 * bf2f(f0.w);
        z += p0;
    }
    const float rz = 1.f / z;
    *(float4*)op = make_float4(a0 * rz + b4.x, a1 * rz + b4.y,
                               a2 * rz + b4.z, a3 * rz + b4.w);
}

// ---------------------------------------------------------------------------
extern "C" void kernel_launch(void* const* d_in, const int* in_sizes, int n_in,
                              void* d_out, int out_size, void* d_ws, size_t ws_size,
                              hipStream_t stream) {
    const float* feat     = (const float*)d_in[0];
    const float* ee       = (const float*)d_in[1];
    const int*   src      = (const int*)d_in[2];
    const int*   dst      = (const int*)d_in[3];
    const int*   etype    = (const int*)d_in[4];
    const float* W_src    = (const float*)d_in[5];
    const float* attn_l   = (const float*)d_in[6];
    const float* attn_r   = (const float*)d_in[7];
    const float* attn_e   = (const float*)d_in[8];
    const float* W_e      = (const float*)d_in[9];
    const float* type_emb = (const float*)d_in[10];
    const float* W_et     = (const float*)d_in[11];
    const float* attn_et  = (const float*)d_in[12];
    const float* bias     = (const float*)d_in[13];
    float* out = (float*)d_out;

    char* ws = (char*)d_ws;
    size_t o = 0;
    auto alloc = [&](size_t bytes) -> void* {
        void* p = ws + o;
        o = (o + bytes + 255) & ~(size_t)255;
        return p;
    };
    unsigned short* fsb  = (unsigned short*)alloc((size_t)N_NODES * HF * 2); // 25.6 MB
    unsigned short* pexp = (unsigned short*)alloc((size_t)E_EDGES * 8 * 2);  // 12.8 MB
    float* el    = (float*)alloc((size_t)N_NODES * 8 * 4);
    float* er    = (float*)alloc((size_t)N_NODES * 8 * 4);
    int*   off   = (int*)alloc((size_t)(N_NODES + 1) * 4);
    int*   counts= (int*)alloc(T_TYPES * 4);
    float* M     = (float*)alloc(64 * 4);
    float* ttab  = (float*)alloc(64 * 4);
    float* w     = (float*)alloc(T_TYPES * 4);

    hipMemsetAsync(counts, 0, T_TYPES * sizeof(int), stream);
    hist_kernel<<<256, 256, 0, stream>>>(etype, counts);
    tables_kernel<<<1, 256, 0, stream>>>(attn_e, W_e, attn_et, W_et, type_emb,
                                         counts, M, ttab, w);
    node_gemm<<<512, 256, 0, stream>>>(feat, W_src, attn_l, attn_r, fsb, el, er);
    build_offsets<<<(N_NODES + 1 + 255) / 256, 256, 0, stream>>>(dst, off);
    edge_kernel<<<(E_EDGES + 255) / 256, 256, 0, stream>>>(
        ee, src, dst, etype, el, er, M, ttab, w, pexp);
    agg_kernel<<<(N_NODES + 3) / 4, 256, 0, stream>>>(pexp, fsb, src, off, bias, out);
}

// Round 3
// 170.135 us; speedup vs baseline: 1.6092x; 1.5703x over previous
//
#include <hip/hip_runtime.h>
#include <math.h>

#define N_NODES 50000
#define D_IN    128
#define E_EDGES 800000
#define H_HEADS 8
#define F_FEAT  32
#define T_TYPES 8
#define HF      256
#define NEG_SLOPE 0.2f
#define HIST_BLOCKS 256

__device__ inline float bf2f(unsigned short u) {
    union { unsigned int i; float f; } v; v.i = ((unsigned int)u) << 16; return v.f;
}
__device__ inline unsigned short f2bf(float f) {
    unsigned int x = __float_as_uint(f);
    unsigned int r = (x + 0x7fffu + ((x >> 16) & 1u)) >> 16;
    return (unsigned short)r;
}

// ---------------------------------------------------------------------------
// Kernel 1: per-block partial histogram of edge types — NO global atomics.
//   partials[b*8 + t] = count of type t in block b's range.
// ---------------------------------------------------------------------------
__global__ __launch_bounds__(256) void hist_part(const int* __restrict__ etype,
                                                 int* __restrict__ partials) {
    __shared__ int sw[4][8];
    int c[8] = {0,0,0,0,0,0,0,0};
    const int stride = gridDim.x * blockDim.x;
    for (int e = blockIdx.x * blockDim.x + threadIdx.x; e < E_EDGES; e += stride) {
        int ty = etype[e];
#pragma unroll
        for (int t = 0; t < 8; ++t) c[t] += (ty == t) ? 1 : 0;
    }
#pragma unroll
    for (int t = 0; t < 8; ++t) {
        c[t] += __shfl_xor(c[t], 1);  c[t] += __shfl_xor(c[t], 2);
        c[t] += __shfl_xor(c[t], 4);  c[t] += __shfl_xor(c[t], 8);
        c[t] += __shfl_xor(c[t], 16); c[t] += __shfl_xor(c[t], 32);
    }
    const int wid = threadIdx.x >> 6, l = threadIdx.x & 63;
    if (l == 0) {
#pragma unroll
        for (int t = 0; t < 8; ++t) sw[wid][t] = c[t];
    }
    __syncthreads();
    if (threadIdx.x < 8) {
        int t = threadIdx.x;
        partials[blockIdx.x * 8 + t] = sw[0][t] + sw[1][t] + sw[2][t] + sw[3][t];
    }
}

// ---------------------------------------------------------------------------
// Kernel 2: small precomputed tables + histogram reduce
//   M[h][j]    = sum_f attn_e[h,f] * W_e[h*32+f, j]
//   ttab[t][h] = sum_f2 type_emb[t,f2] * q[h,f2],  q[h,f2]=sum_f attn_et*W_et
//   w[t]       = E / (T * counts[t]),  counts = reduce(partials)
// ---------------------------------------------------------------------------
__global__ __launch_bounds__(256) void tables_kernel(const float* __restrict__ attn_e,
                              const float* __restrict__ W_e,
                              const float* __restrict__ attn_et,
                              const float* __restrict__ W_et,
                              const float* __restrict__ type_emb,
                              const int* __restrict__ partials,
                              float* __restrict__ M, float* __restrict__ ttab,
                              float* __restrict__ w) {
    __shared__ float q[8][32];
    int t = threadIdx.x;
    {   // phase 1: q[h][f2], thread = h*32+f2, coalesced W_et reads
        int h = t >> 5, f2 = t & 31;
        float s = 0.f;
#pragma unroll 8
        for (int f = 0; f < F_FEAT; ++f)
            s += attn_et[h * 32 + f] * W_et[(h * 32 + f) * 32 + f2];
        q[h][f2] = s;
    }
    __syncthreads();
    if (t < 64) {
        int h = t >> 3, j = t & 7;
        float m = 0.f;
#pragma unroll 8
        for (int f = 0; f < F_FEAT; ++f)
            m += attn_e[h * 32 + f] * W_e[(h * 32 + f) * 8 + j];
        M[h * 8 + j] = m;
        float tt = 0.f;
#pragma unroll 8
        for (int f2 = 0; f2 < F_FEAT; ++f2)
            tt += type_emb[j * 32 + f2] * q[h][f2];
        ttab[j * 8 + h] = tt;   // [type][head]
    }
    if (t < 64) {
        // histogram reduce: bin j = t&7, chunk = t>>3 covers 32 blocks
        int j = t & 7, chunk = t >> 3;
        int c = 0;
#pragma unroll 8
        for (int b = 0; b < HIST_BLOCKS / 8; ++b)
            c += partials[(chunk * (HIST_BLOCKS / 8) + b) * 8 + j];
        c += __shfl_xor(c, 8); c += __shfl_xor(c, 16); c += __shfl_xor(c, 32);
        if (t < 8) {
            if (c < 1) c = 1;
            w[t] = (float)E_EDGES / (8.0f * (float)c);
        }
    }
}

// ---------------------------------------------------------------------------
// Kernel 3: node transform fs = feat @ W_src^T (+ fused el, er), bf16 fs out.
//   Column-split: block parity picks 128 of 256 cols -> 77.8 KB LDS,
//   2 blocks/CU, 2 waves/SIMD. Lane = 2 nodes x 4 cols.
// ---------------------------------------------------------------------------
__global__ __launch_bounds__(256) void node_gemm(const float* __restrict__ feat,
                                                 const float* __restrict__ W,
                                                 const float* __restrict__ attn_l,
                                                 const float* __restrict__ attn_r,
                                                 unsigned short* __restrict__ fsb,
                                                 float* __restrict__ el,
                                                 float* __restrict__ er) {
    __shared__ float Wt[D_IN][132];  // Wt[k][cl] = W[cbase+cl][k]
    __shared__ float ft[D_IN][20];   // ft[k][j], 16 nodes + pad
    const int t = threadIdx.x;
    const int ch = blockIdx.x & 1;   // column half: cols [128*ch, 128*ch+128)
    const int cbase = ch * 128;
    for (int i = 0; i < 64; ++i) {
        int idx = i * 256 + t;
        int cl = idx >> 7;
        int k  = idx & 127;
        Wt[k][cl] = W[(cbase + cl) * D_IN + k];
    }
    const int wid = t >> 6;
    const int l = t & 63;
    const int lc = l & 31;
    const int c0 = 4 * lc;
    const int jb = 4 * wid + 2 * (l >> 5);
    const float4 al = *(const float4*)&attn_l[cbase + c0];
    const float4 ar = *(const float4*)&attn_r[cbase + c0];
    const int h = lc >> 3;

    for (int g = blockIdx.x >> 1; g < N_NODES / 16; g += gridDim.x >> 1) {
        const int nbase = g * 16;
        __syncthreads();
        for (int i = 0; i < 8; ++i) {
            int idx = i * 256 + t;
            int j = idx >> 7, k = idx & 127;
            ft[k][j] = feat[(nbase + j) * D_IN + k];
        }
        __syncthreads();

        float acc[2][4];
#pragma unroll
        for (int j = 0; j < 2; ++j)
#pragma unroll
            for (int c = 0; c < 4; ++c) acc[j][c] = 0.f;
#pragma unroll 4
        for (int k = 0; k < D_IN; ++k) {
            float4 wv = *(const float4*)&Wt[k][c0];
            float2 fv = *(const float2*)&ft[k][jb];
            acc[0][0] += fv.x * wv.x; acc[0][1] += fv.x * wv.y;
            acc[0][2] += fv.x * wv.z; acc[0][3] += fv.x * wv.w;
            acc[1][0] += fv.y * wv.x; acc[1][1] += fv.y * wv.y;
            acc[1][2] += fv.y * wv.z; acc[1][3] += fv.y * wv.w;
        }
#pragma unroll
        for (int j = 0; j < 2; ++j) {
            const int n = nbase + jb + j;
            float pl = acc[j][0]*al.x + acc[j][1]*al.y + acc[j][2]*al.z + acc[j][3]*al.w;
            float pr = acc[j][0]*ar.x + acc[j][1]*ar.y + acc[j][2]*ar.z + acc[j][3]*ar.w;
            pl += __shfl_xor(pl, 1); pr += __shfl_xor(pr, 1);
            pl += __shfl_xor(pl, 2); pr += __shfl_xor(pr, 2);
            pl += __shfl_xor(pl, 4); pr += __shfl_xor(pr, 4);
            ushort4 u;
            u.x = f2bf(acc[j][0]); u.y = f2bf(acc[j][1]);
            u.z = f2bf(acc[j][2]); u.w = f2bf(acc[j][3]);
            *(ushort4*)&fsb[(size_t)n * HF + cbase + c0] = u;
            if ((l & 7) == 0) {
                el[n * 8 + ch * 4 + h] = pl;
                er[n * 8 + ch * 4 + h] = pr;
            }
        }
    }
}

// ---------------------------------------------------------------------------
// Kernel 4: CSR row offsets from sorted dst
// ---------------------------------------------------------------------------
__global__ __launch_bounds__(256) void build_offsets(const int* __restrict__ dst,
                                                     int* __restrict__ off) {
    int n = blockIdx.x * blockDim.x + threadIdx.x;
    if (n > N_NODES) return;
    int lo = 0, hi = E_EDGES;
    while (lo < hi) {
        int mid = (lo + hi) >> 1;
        if (dst[mid] < n) lo = mid + 1; else hi = mid;
    }
    off[n] = lo;
}

// ---------------------------------------------------------------------------
// Kernel 5: per-edge p = exp(leakyrelu(w*(el+er+escore+tscore))), bf16 out.
// ---------------------------------------------------------------------------
__global__ __launch_bounds__(256) void edge_kernel(const float* __restrict__ ee,
        const int* __restrict__ src, const int* __restrict__ dst,
        const int* __restrict__ etype, const float* __restrict__ el,
        const float* __restrict__ er, const float* __restrict__ M,
        const float* __restrict__ ttab, const float* __restrict__ w,
        unsigned short* __restrict__ pexp) {
    __shared__ float sM[64], sT[64], sw[8];
    int t = threadIdx.x;
    if (t < 64) { sM[t] = M[t]; sT[t] = ttab[t]; }
    if (t < 8) sw[t] = w[t];
    __syncthreads();
    int e = blockIdx.x * 256 + t;
    if (e >= E_EDGES) return;
    int s = src[e], d = dst[e], ty = etype[e];
    float4 e0 = *(const float4*)&ee[(size_t)e * 8];
    float4 e1 = *(const float4*)&ee[(size_t)e * 8 + 4];
    float4 l0 = *(const float4*)&el[s * 8];
    float4 l1 = *(const float4*)&el[s * 8 + 4];
    float4 r0 = *(const float4*)&er[d * 8];
    float4 r1 = *(const float4*)&er[d * 8 + 4];
    float wt = sw[ty];
    float lv[8] = {l0.x,l0.y,l0.z,l0.w,l1.x,l1.y,l1.z,l1.w};
    float rv[8] = {r0.x,r0.y,r0.z,r0.w,r1.x,r1.y,r1.z,r1.w};
    unsigned int o[4];
#pragma unroll
    for (int hp = 0; hp < 4; ++hp) {
        float p2[2];
#pragma unroll
        for (int i = 0; i < 2; ++i) {
            int h = hp * 2 + i;
            float sc = lv[h] + rv[h] + sT[ty * 8 + h];
            sc += e0.x*sM[h*8+0] + e0.y*sM[h*8+1] + e0.z*sM[h*8+2] + e0.w*sM[h*8+3]
                + e1.x*sM[h*8+4] + e1.y*sM[h*8+5] + e1.z*sM[h*8+6] + e1.w*sM[h*8+7];
            sc *= wt;
            sc = (sc >= 0.f) ? sc : NEG_SLOPE * sc;
            p2[i] = __expf(sc);
        }
        o[hp] = (unsigned int)f2bf(p2[0]) | ((unsigned int)f2bf(p2[1]) << 16);
    }
    *(uint4*)&pexp[(size_t)e * 8] = make_uint4(o[0], o[1], o[2], o[3]);
}

// ---------------------------------------------------------------------------
// Kernel 6: single-pass softmax-normalized aggregation. One wave per dst node.
// ---------------------------------------------------------------------------
__global__ __launch_bounds__(256) void agg_kernel(const unsigned short* __restrict__ pexp,
        const unsigned short* __restrict__ fsb, const int* __restrict__ src,
        const int* __restrict__ off, const float* __restrict__ bias,
        float* __restrict__ out) {
    const int wid = threadIdx.x >> 6;
    const int l = threadIdx.x & 63;
    const int n = blockIdx.x * 4 + wid;
    if (n >= N_NODES) return;
    const int beg = off[n], end = off[n + 1];
    const int c0 = 4 * l;
    const int h = l >> 3;
    const float4 b4 = *(const float4*)&bias[c0];
    float* op = &out[(size_t)n * HF + c0];
    if (beg == end) { *(float4*)op = b4; return; }
    float a0 = 0.f, a1 = 0.f, a2 = 0.f, a3 = 0.f, z = 0.f;
    int e = beg;
    for (; e + 1 < end; e += 2) {
        int s0 = src[e], s1 = src[e + 1];
        float p0 = bf2f(pexp[(size_t)e * 8 + h]);
        float p1 = bf2f(pexp[(size_t)(e + 1) * 8 + h]);
        ushort4 f0 = *(const ushort4*)&fsb[(size_t)s0 * HF + c0];
        ushort4 f1 = *(const ushort4*)&fsb[(size_t)s1 * HF + c0];
        a0 += p0 * bf2f(f0.x); a1 += p0 * bf2f(f0.y);
        a2 += p0 * bf2f(f0.z); a3 += p0 * bf2f(f0.w);
        z += p0;
        a0 += p1 * bf2f(f1.x); a1 += p1 * bf2f(f1.y);
        a2 += p1 * bf2f(f1.z); a3 += p1 * bf2f(f1.w);
        z += p1;
    }
    if (e < end) {
        int s0 = src[e];
        float p0 = bf2f(pexp[(size_t)e * 8 + h]);
        ushort4 f0 = *(const ushort4*)&fsb[(size_t)s0 * HF + c0];
        a0 += p0 * bf2f(f0.x); a1 += p0 * bf2f(f0.y);
        a2 += p0 * bf2f(f0.z); a3 += p0 * bf2f(f0.w);
        z += p0;
    }
    const float rz = 1.f / z;
    *(float4*)op = make_float4(a0 * rz + b4.x, a1 * rz + b4.y,
                               a2 * rz + b4.z, a3 * rz + b4.w);
}

// ---------------------------------------------------------------------------
extern "C" void kernel_launch(void* const* d_in, const int* in_sizes, int n_in,
                              void* d_out, int out_size, void* d_ws, size_t ws_size,
                              hipStream_t stream) {
    const float* feat     = (const float*)d_in[0];
    const float* ee       = (const float*)d_in[1];
    const int*   src      = (const int*)d_in[2];
    const int*   dst      = (const int*)d_in[3];
    const int*   etype    = (const int*)d_in[4];
    const float* W_src    = (const float*)d_in[5];
    const float* attn_l   = (const float*)d_in[6];
    const float* attn_r   = (const float*)d_in[7];
    const float* attn_e   = (const float*)d_in[8];
    const float* W_e      = (const float*)d_in[9];
    const float* type_emb = (const float*)d_in[10];
    const float* W_et     = (const float*)d_in[11];
    const float* attn_et  = (const float*)d_in[12];
    const float* bias     = (const float*)d_in[13];
    float* out = (float*)d_out;

    char* ws = (char*)d_ws;
    size_t o = 0;
    auto alloc = [&](size_t bytes) -> void* {
        void* p = ws + o;
        o = (o + bytes + 255) & ~(size_t)255;
        return p;
    };
    unsigned short* fsb  = (unsigned short*)alloc((size_t)N_NODES * HF * 2); // 25.6 MB
    unsigned short* pexp = (unsigned short*)alloc((size_t)E_EDGES * 8 * 2);  // 12.8 MB
    float* el    = (float*)alloc((size_t)N_NODES * 8 * 4);
    float* er    = (float*)alloc((size_t)N_NODES * 8 * 4);
    int*   off   = (int*)alloc((size_t)(N_NODES + 1) * 4);
    int*   partials = (int*)alloc((size_t)HIST_BLOCKS * 8 * 4);
    float* M     = (float*)alloc(64 * 4);
    float* ttab  = (float*)alloc(64 * 4);
    float* w     = (float*)alloc(T_TYPES * 4);

    hist_part<<<HIST_BLOCKS, 256, 0, stream>>>(etype, partials);
    tables_kernel<<<1, 256, 0, stream>>>(attn_e, W_e, attn_et, W_et, type_emb,
                                         partials, M, ttab, w);
    node_gemm<<<512, 256, 0, stream>>>(feat, W_src, attn_l, attn_r, fsb, el, er);
    build_offsets<<<(N_NODES + 1 + 255) / 256, 256, 0, stream>>>(dst, off);
    edge_kernel<<<(E_EDGES + 255) / 256, 256, 0, stream>>>(
        ee, src, dst, etype, el, er, M, ttab, w, pexp);
    agg_kernel<<<(N_NODES + 3) / 4, 256, 0, stream>>>(pexp, fsb, src, off, bias, out);
}

// Round 5
// 134.748 us; speedup vs baseline: 2.0318x; 1.2626x over previous
//
#include <hip/hip_runtime.h>
#include <math.h>

#define N_NODES 50000
#define D_IN    128
#define E_EDGES 800000
#define H_HEADS 8
#define F_FEAT  32
#define T_TYPES 8
#define HF      256
#define NEG_SLOPE 0.2f
#define HIST_BLOCKS 256

using short8 = __attribute__((__ext_vector_type__(8))) short;
using f32x4  = __attribute__((__ext_vector_type__(4))) float;

__device__ inline float bf2f(unsigned short u) {
    union { unsigned int i; float f; } v; v.i = ((unsigned int)u) << 16; return v.f;
}
__device__ inline unsigned short f2bf(float f) {
    unsigned int x = __float_as_uint(f);
    unsigned int r = (x + 0x7fffu + ((x >> 16) & 1u)) >> 16;
    return (unsigned short)r;
}
__device__ inline unsigned int pk2bf(float a, float b) {
    return (unsigned int)f2bf(a) | ((unsigned int)f2bf(b) << 16);
}

// ---------------------------------------------------------------------------
// Kernel 1: per-block partial histogram of edge types — NO global atomics.
// ---------------------------------------------------------------------------
__global__ __launch_bounds__(256) void hist_part(const int* __restrict__ etype,
                                                 int* __restrict__ partials) {
    __shared__ int sw[4][8];
    int c[8] = {0,0,0,0,0,0,0,0};
    const int stride = gridDim.x * blockDim.x;
    for (int e = blockIdx.x * blockDim.x + threadIdx.x; e < E_EDGES; e += stride) {
        int ty = etype[e];
#pragma unroll
        for (int t = 0; t < 8; ++t) c[t] += (ty == t) ? 1 : 0;
    }
#pragma unroll
    for (int t = 0; t < 8; ++t) {
        c[t] += __shfl_xor(c[t], 1);  c[t] += __shfl_xor(c[t], 2);
        c[t] += __shfl_xor(c[t], 4);  c[t] += __shfl_xor(c[t], 8);
        c[t] += __shfl_xor(c[t], 16); c[t] += __shfl_xor(c[t], 32);
    }
    const int wid = threadIdx.x >> 6, l = threadIdx.x & 63;
    if (l == 0) {
#pragma unroll
        for (int t = 0; t < 8; ++t) sw[wid][t] = c[t];
    }
    __syncthreads();
    if (threadIdx.x < 8) {
        int t = threadIdx.x;
        partials[blockIdx.x * 8 + t] = sw[0][t] + sw[1][t] + sw[2][t] + sw[3][t];
    }
}

// ---------------------------------------------------------------------------
// Kernel 2: small precomputed tables + histogram reduce
// ---------------------------------------------------------------------------
__global__ __launch_bounds__(256) void tables_kernel(const float* __restrict__ attn_e,
                              const float* __restrict__ W_e,
                              const float* __restrict__ attn_et,
                              const float* __restrict__ W_et,
                              const float* __restrict__ type_emb,
                              const int* __restrict__ partials,
                              float* __restrict__ M, float* __restrict__ ttab,
                              float* __restrict__ w) {
    __shared__ float q[8][32];
    int t = threadIdx.x;
    {   // phase 1: q[h][f2], thread = h*32+f2, coalesced W_et reads
        int h = t >> 5, f2 = t & 31;
        float s = 0.f;
#pragma unroll 8
        for (int f = 0; f < F_FEAT; ++f)
            s += attn_et[h * 32 + f] * W_et[(h * 32 + f) * 32 + f2];
        q[h][f2] = s;
    }
    __syncthreads();
    if (t < 64) {
        int h = t >> 3, j = t & 7;
        float m = 0.f;
#pragma unroll 8
        for (int f = 0; f < F_FEAT; ++f)
            m += attn_e[h * 32 + f] * W_e[(h * 32 + f) * 8 + j];
        M[h * 8 + j] = m;
        float tt = 0.f;
#pragma unroll 8
        for (int f2 = 0; f2 < F_FEAT; ++f2)
            tt += type_emb[j * 32 + f2] * q[h][f2];
        ttab[j * 8 + h] = tt;   // [type][head]
    }
    if (t < 64) {
        int j = t & 7, chunk = t >> 3;
        int c = 0;
#pragma unroll 8
        for (int b = 0; b < HIST_BLOCKS / 8; ++b)
            c += partials[(chunk * (HIST_BLOCKS / 8) + b) * 8 + j];
        c += __shfl_xor(c, 8); c += __shfl_xor(c, 16); c += __shfl_xor(c, 32);
        if (t < 8) {
            if (c < 1) c = 1;
            w[t] = (float)E_EDGES / (8.0f * (float)c);
        }
    }
}

// ---------------------------------------------------------------------------
// Kernel 3: MFMA node transform fs = feat @ W_src^T (+ fused el, er).
//   bf16 inputs, fp32 accumulate, bf16 fs out (fp32 el/er from accumulators).
//   Block = 4 waves x 16 nodes = 64 nodes; W bf16 in 64KB LDS, XOR-swizzled
//   (ushort idx ^= (n&7)<<3) so B-frag ds_read_b128 avoids 16-way conflicts.
//   A and B fragments use the SAME (lane-group, elem)->k mapping, so the MFMA
//   contraction is exact regardless of the HW's internal k layout; only the
//   C/D layout (m89-verified: col=l&15, row=(l>>4)*4+reg) must be exact.
// ---------------------------------------------------------------------------
__global__ __launch_bounds__(256) void node_gemm(const float* __restrict__ feat,
                                                 const float* __restrict__ W,
                                                 const float* __restrict__ attn_l,
                                                 const float* __restrict__ attn_r,
                                                 unsigned short* __restrict__ fsb,
                                                 float* __restrict__ el,
                                                 float* __restrict__ er) {
    __shared__ unsigned short Wl[HF * D_IN];   // 64 KB bf16, swizzled
    const int t = threadIdx.x;
    // stage W -> bf16 LDS: 256 rows x 16 chunks of 8 = 4096 slots (16 iters)
    for (int i = 0; i < 16; ++i) {
        int slot = i * 256 + t;
        int n = slot >> 4, k16 = slot & 15;    // row n, 8-elem chunk k16
        const float* wp = W + (size_t)n * D_IN + k16 * 8;
        float4 w0 = *(const float4*)wp;
        float4 w1 = *(const float4*)(wp + 4);
        union { unsigned int u[4]; short8 s; } ua;
        ua.u[0] = pk2bf(w0.x, w0.y); ua.u[1] = pk2bf(w0.z, w0.w);
        ua.u[2] = pk2bf(w1.x, w1.y); ua.u[3] = pk2bf(w1.z, w1.w);
        int idx = n * D_IN + ((k16 * 8) ^ ((n & 7) << 3));
        *(short8*)&Wl[idx] = ua.s;
    }
    __syncthreads();

    const int wid = t >> 6, l = t & 63;
    const int r16 = l & 15, kq = l >> 4;       // kq in 0..3
    const int node0 = blockIdx.x * 64 + wid * 16;
    int arow = node0 + r16;
    if (arow >= N_NODES) arow = N_NODES - 1;   // clamp; stores guarded below
    const float* fp = feat + (size_t)arow * D_IN + kq * 8;

    f32x4 acc[16];
#pragma unroll
    for (int i = 0; i < 16; ++i) acc[i] = (f32x4){0.f, 0.f, 0.f, 0.f};

#pragma unroll
    for (int kc = 0; kc < 4; ++kc) {
        float4 a0 = *(const float4*)(fp + kc * 32);
        float4 a1 = *(const float4*)(fp + kc * 32 + 4);
        union { unsigned int u[4]; short8 s; } ua;
        ua.u[0] = pk2bf(a0.x, a0.y); ua.u[1] = pk2bf(a0.z, a0.w);
        ua.u[2] = pk2bf(a1.x, a1.y); ua.u[3] = pk2bf(a1.z, a1.w);
        short8 af = ua.s;
#pragma unroll
        for (int nsub = 0; nsub < 16; ++nsub) {
            int n = nsub * 16 + r16;
            int idx = n * D_IN + ((kc * 32 + kq * 8) ^ ((n & 7) << 3));
            short8 bf = *(short8*)&Wl[idx];
            acc[nsub] = __builtin_amdgcn_mfma_f32_16x16x32_bf16(af, bf, acc[nsub], 0, 0, 0);
        }
    }

    // epilogue 1: el/er from fp32 accumulators (head h = nsub>>1)
    const int nodeb = node0 + kq * 4;          // this lane's 4 acc rows
#pragma unroll
    for (int h = 0; h < 8; ++h) {
        float al0 = attn_l[h * 32 + r16],      al1 = attn_l[h * 32 + 16 + r16];
        float ar0 = attn_r[h * 32 + r16],      ar1 = attn_r[h * 32 + 16 + r16];
        float ev[4], rv[4];
#pragma unroll
        for (int g = 0; g < 4; ++g) {
            ev[g] = acc[2 * h][g] * al0 + acc[2 * h + 1][g] * al1;
            rv[g] = acc[2 * h][g] * ar0 + acc[2 * h + 1][g] * ar1;
        }
#pragma unroll
        for (int g = 0; g < 4; ++g) {
            ev[g] += __shfl_xor(ev[g], 1); ev[g] += __shfl_xor(ev[g], 2);
            ev[g] += __shfl_xor(ev[g], 4); ev[g] += __shfl_xor(ev[g], 8);
            rv[g] += __shfl_xor(rv[g], 1); rv[g] += __shfl_xor(rv[g], 2);
            rv[g] += __shfl_xor(rv[g], 4); rv[g] += __shfl_xor(rv[g], 8);
        }
        if (r16 == 0) {
#pragma unroll
            for (int g = 0; g < 4; ++g) {
                int nd = nodeb + g;
                if (nd < N_NODES) {
                    el[nd * 8 + h] = ev[g];
                    er[nd * 8 + h] = rv[g];
                }
            }
        }
    }
    // epilogue 2: fs bf16 stores
#pragma unroll
    for (int nsub = 0; nsub < 16; ++nsub) {
        int col = nsub * 16 + r16;
#pragma unroll
        for (int g = 0; g < 4; ++g) {
            int nd = nodeb + g;
            if (nd < N_NODES) fsb[(size_t)nd * HF + col] = f2bf(acc[nsub][g]);
        }
    }
}

// ---------------------------------------------------------------------------
// Kernel 4: CSR row offsets from sorted dst
// ---------------------------------------------------------------------------
__global__ __launch_bounds__(256) void build_offsets(const int* __restrict__ dst,
                                                     int* __restrict__ off) {
    int n = blockIdx.x * blockDim.x + threadIdx.x;
    if (n > N_NODES) return;
    int lo = 0, hi = E_EDGES;
    while (lo < hi) {
        int mid = (lo + hi) >> 1;
        if (dst[mid] < n) lo = mid + 1; else hi = mid;
    }
    off[n] = lo;
}

// ---------------------------------------------------------------------------
// Kernel 5: per-edge p = exp(leakyrelu(w*(el+er+escore+tscore))), bf16 out.
// ---------------------------------------------------------------------------
__global__ __launch_bounds__(256) void edge_kernel(const float* __restrict__ ee,
        const int* __restrict__ src, const int* __restrict__ dst,
        const int* __restrict__ etype, const float* __restrict__ el,
        const float* __restrict__ er, const float* __restrict__ M,
        const float* __restrict__ ttab, const float* __restrict__ w,
        unsigned short* __restrict__ pexp) {
    __shared__ float sM[64], sT[64], sw[8];
    int t = threadIdx.x;
    if (t < 64) { sM[t] = M[t]; sT[t] = ttab[t]; }
    if (t < 8) sw[t] = w[t];
    __syncthreads();
    int e = blockIdx.x * 256 + t;
    if (e >= E_EDGES) return;
    int s = src[e], d = dst[e], ty = etype[e];
    float4 e0 = *(const float4*)&ee[(size_t)e * 8];
    float4 e1 = *(const float4*)&ee[(size_t)e * 8 + 4];
    float4 l0 = *(const float4*)&el[s * 8];
    float4 l1 = *(const float4*)&el[s * 8 + 4];
    float4 r0 = *(const float4*)&er[d * 8];
    float4 r1 = *(const float4*)&er[d * 8 + 4];
    float wt = sw[ty];
    float lv[8] = {l0.x,l0.y,l0.z,l0.w,l1.x,l1.y,l1.z,l1.w};
    float rv[8] = {r0.x,r0.y,r0.z,r0.w,r1.x,r1.y,r1.z,r1.w};
    unsigned int o[4];
#pragma unroll
    for (int hp = 0; hp < 4; ++hp) {
        float p2[2];
#pragma unroll
        for (int i = 0; i < 2; ++i) {
            int h = hp * 2 + i;
            float sc = lv[h] + rv[h] + sT[ty * 8 + h];
            sc += e0.x*sM[h*8+0] + e0.y*sM[h*8+1] + e0.z*sM[h*8+2] + e0.w*sM[h*8+3]
                + e1.x*sM[h*8+4] + e1.y*sM[h*8+5] + e1.z*sM[h*8+6] + e1.w*sM[h*8+7];
            sc *= wt;
            sc = (sc >= 0.f) ? sc : NEG_SLOPE * sc;
            p2[i] = __expf(sc);
        }
        o[hp] = (unsigned int)f2bf(p2[0]) | ((unsigned int)f2bf(p2[1]) << 16);
    }
    *(uint4*)&pexp[(size_t)e * 8] = make_uint4(o[0], o[1], o[2], o[3]);
}

// ---------------------------------------------------------------------------
// Kernel 6: single-pass softmax-normalized aggregation. One wave per dst node.
// ---------------------------------------------------------------------------
__global__ __launch_bounds__(256) void agg_kernel(const unsigned short* __restrict__ pexp,
        const unsigned short* __restrict__ fsb, const int* __restrict__ src,
        const int* __restrict__ off, const float* __restrict__ bias,
        float* __restrict__ out) {
    const int wid = threadIdx.x >> 6;
    const int l = threadIdx.x & 63;
    const int n = blockIdx.x * 4 + wid;
    if (n >= N_NODES) return;
    const int beg = off[n], end = off[n + 1];
    const int c0 = 4 * l;
    const int h = l >> 3;
    const float4 b4 = *(const float4*)&bias[c0];
    float* op = &out[(size_t)n * HF + c0];
    if (beg == end) { *(float4*)op = b4; return; }
    float a0 = 0.f, a1 = 0.f, a2 = 0.f, a3 = 0.f, z = 0.f;
    int e = beg;
    for (; e + 1 < end; e += 2) {
        int s0 = src[e], s1 = src[e + 1];
        float p0 = bf2f(pexp[(size_t)e * 8 + h]);
        float p1 = bf2f(pexp[(size_t)(e + 1) * 8 + h]);
        ushort4 f0 = *(const ushort4*)&fsb[(size_t)s0 * HF + c0];
        ushort4 f1 = *(const ushort4*)&fsb[(size_t)s1 * HF + c0];
        a0 += p0 * bf2f(f0.x); a1 += p0 * bf2f(f0.y);
        a2 += p0 * bf2f(f0.z); a3 += p0 * bf2f(f0.w);
        z += p0;
        a0 += p1 * bf2f(f1.x); a1 += p1 * bf2f(f1.y);
        a2 += p1 * bf2f(f1.z); a3 += p1 * bf2f(f1.w);
        z += p1;
    }
    if (e < end) {
        int s0 = src[e];
        float p0 = bf2f(pexp[(size_t)e * 8 + h]);
        ushort4 f0 = *(const ushort4*)&fsb[(size_t)s0 * HF + c0];
        a0 += p0 * bf2f(f0.x); a1 += p0 * bf2f(f0.y);
        a2 += p0 * bf2f(f0.z); a3 += p0 * bf2f(f0.w);
        z += p0;
    }
    const float rz = 1.f / z;
    *(float4*)op = make_float4(a0 * rz + b4.x, a1 * rz + b4.y,
                               a2 * rz + b4.z, a3 * rz + b4.w);
}

// ---------------------------------------------------------------------------
extern "C" void kernel_launch(void* const* d_in, const int* in_sizes, int n_in,
                              void* d_out, int out_size, void* d_ws, size_t ws_size,
                              hipStream_t stream) {
    const float* feat     = (const float*)d_in[0];
    const float* ee       = (const float*)d_in[1];
    const int*   src      = (const int*)d_in[2];
    const int*   dst      = (const int*)d_in[3];
    const int*   etype    = (const int*)d_in[4];
    const float* W_src    = (const float*)d_in[5];
    const float* attn_l   = (const float*)d_in[6];
    const float* attn_r   = (const float*)d_in[7];
    const float* attn_e   = (const float*)d_in[8];
    const float* W_e      = (const float*)d_in[9];
    const float* type_emb = (const float*)d_in[10];
    const float* W_et     = (const float*)d_in[11];
    const float* attn_et  = (const float*)d_in[12];
    const float* bias     = (const float*)d_in[13];
    float* out = (float*)d_out;

    char* ws = (char*)d_ws;
    size_t o = 0;
    auto alloc = [&](size_t bytes) -> void* {
        void* p = ws + o;
        o = (o + bytes + 255) & ~(size_t)255;
        return p;
    };
    unsigned short* fsb  = (unsigned short*)alloc((size_t)N_NODES * HF * 2); // 25.6 MB
    unsigned short* pexp = (unsigned short*)alloc((size_t)E_EDGES * 8 * 2);  // 12.8 MB
    float* el    = (float*)alloc((size_t)N_NODES * 8 * 4);
    float* er    = (float*)alloc((size_t)N_NODES * 8 * 4);
    int*   off   = (int*)alloc((size_t)(N_NODES + 1) * 4);
    int*   partials = (int*)alloc((size_t)HIST_BLOCKS * 8 * 4);
    float* M     = (float*)alloc(64 * 4);
    float* ttab  = (float*)alloc(64 * 4);
    float* w     = (float*)alloc(T_TYPES * 4);

    hist_part<<<HIST_BLOCKS, 256, 0, stream>>>(etype, partials);
    tables_kernel<<<1, 256, 0, stream>>>(attn_e, W_e, attn_et, W_et, type_emb,
                                         partials, M, ttab, w);
    node_gemm<<<(N_NODES + 63) / 64, 256, 0, stream>>>(feat, W_src, attn_l, attn_r,
                                                       fsb, el, er);
    build_offsets<<<(N_NODES + 1 + 255) / 256, 256, 0, stream>>>(dst, off);
    edge_kernel<<<(E_EDGES + 255) / 256, 256, 0, stream>>>(
        ee, src, dst, etype, el, er, M, ttab, w, pexp);
    agg_kernel<<<(N_NODES + 3) / 4, 256, 0, stream>>>(pexp, fsb, src, off, bias, out);
}

// Round 6
// 128.291 us; speedup vs baseline: 2.1341x; 1.0503x over previous
//
#include <hip/hip_runtime.h>
#include <math.h>

#define N_NODES 50000
#define D_IN    128
#define E_EDGES 800000
#define H_HEADS 8
#define F_FEAT  32
#define T_TYPES 8
#define HF      256
#define NEG_SLOPE 0.2f
#define HIST_BLOCKS 256

using short8 = __attribute__((__ext_vector_type__(8))) short;
using f32x4  = __attribute__((__ext_vector_type__(4))) float;

__device__ inline float bf2f(unsigned short u) {
    union { unsigned int i; float f; } v; v.i = ((unsigned int)u) << 16; return v.f;
}
__device__ inline unsigned short f2bf(float f) {
    unsigned int x = __float_as_uint(f);
    unsigned int r = (x + 0x7fffu + ((x >> 16) & 1u)) >> 16;
    return (unsigned short)r;
}
__device__ inline unsigned int pk2bf(float a, float b) {
    return (unsigned int)f2bf(a) | ((unsigned int)f2bf(b) << 16);
}

// ---------------------------------------------------------------------------
// Kernel 1: per-block partial histogram of edge types — NO global atomics.
// ---------------------------------------------------------------------------
__global__ __launch_bounds__(256) void hist_part(const int* __restrict__ etype,
                                                 int* __restrict__ partials) {
    __shared__ int sw[4][8];
    int c[8] = {0,0,0,0,0,0,0,0};
    const int stride = gridDim.x * blockDim.x;
    for (int e = blockIdx.x * blockDim.x + threadIdx.x; e < E_EDGES; e += stride) {
        int ty = etype[e];
#pragma unroll
        for (int t = 0; t < 8; ++t) c[t] += (ty == t) ? 1 : 0;
    }
#pragma unroll
    for (int t = 0; t < 8; ++t) {
        c[t] += __shfl_xor(c[t], 1);  c[t] += __shfl_xor(c[t], 2);
        c[t] += __shfl_xor(c[t], 4);  c[t] += __shfl_xor(c[t], 8);
        c[t] += __shfl_xor(c[t], 16); c[t] += __shfl_xor(c[t], 32);
    }
    const int wid = threadIdx.x >> 6, l = threadIdx.x & 63;
    if (l == 0) {
#pragma unroll
        for (int t = 0; t < 8; ++t) sw[wid][t] = c[t];
    }
    __syncthreads();
    if (threadIdx.x < 8) {
        int t = threadIdx.x;
        partials[blockIdx.x * 8 + t] = sw[0][t] + sw[1][t] + sw[2][t] + sw[3][t];
    }
}

// ---------------------------------------------------------------------------
// Kernel 2: small precomputed tables + histogram reduce
// ---------------------------------------------------------------------------
__global__ __launch_bounds__(256) void tables_kernel(const float* __restrict__ attn_e,
                              const float* __restrict__ W_e,
                              const float* __restrict__ attn_et,
                              const float* __restrict__ W_et,
                              const float* __restrict__ type_emb,
                              const int* __restrict__ partials,
                              float* __restrict__ M, float* __restrict__ ttab,
                              float* __restrict__ w) {
    __shared__ float q[8][32];
    int t = threadIdx.x;
    {   // phase 1: q[h][f2], thread = h*32+f2, coalesced W_et reads
        int h = t >> 5, f2 = t & 31;
        float s = 0.f;
#pragma unroll 8
        for (int f = 0; f < F_FEAT; ++f)
            s += attn_et[h * 32 + f] * W_et[(h * 32 + f) * 32 + f2];
        q[h][f2] = s;
    }
    __syncthreads();
    if (t < 64) {
        int h = t >> 3, j = t & 7;
        float m = 0.f;
#pragma unroll 8
        for (int f = 0; f < F_FEAT; ++f)
            m += attn_e[h * 32 + f] * W_e[(h * 32 + f) * 8 + j];
        M[h * 8 + j] = m;
        float tt = 0.f;
#pragma unroll 8
        for (int f2 = 0; f2 < F_FEAT; ++f2)
            tt += type_emb[j * 32 + f2] * q[h][f2];
        ttab[j * 8 + h] = tt;   // [type][head]
    }
    if (t < 64) {
        int j = t & 7, chunk = t >> 3;
        int c = 0;
#pragma unroll 8
        for (int b = 0; b < HIST_BLOCKS / 8; ++b)
            c += partials[(chunk * (HIST_BLOCKS / 8) + b) * 8 + j];
        c += __shfl_xor(c, 8); c += __shfl_xor(c, 16); c += __shfl_xor(c, 32);
        if (t < 8) {
            if (c < 1) c = 1;
            w[t] = (float)E_EDGES / (8.0f * (float)c);
        }
    }
}

// ---------------------------------------------------------------------------
// Kernel 3: MFMA node transform fs = feat @ W_src^T (+ fused el, er).
//   bf16 inputs, fp32 accumulate, bf16 fs out (fp32 el/er from accumulators).
// ---------------------------------------------------------------------------
__global__ __launch_bounds__(256) void node_gemm(const float* __restrict__ feat,
                                                 const float* __restrict__ W,
                                                 const float* __restrict__ attn_l,
                                                 const float* __restrict__ attn_r,
                                                 unsigned short* __restrict__ fsb,
                                                 float* __restrict__ el,
                                                 float* __restrict__ er) {
    __shared__ unsigned short Wl[HF * D_IN];   // 64 KB bf16, swizzled
    const int t = threadIdx.x;
    // stage W -> bf16 LDS: 256 rows x 16 chunks of 8 = 4096 slots (16 iters)
    for (int i = 0; i < 16; ++i) {
        int slot = i * 256 + t;
        int n = slot >> 4, k16 = slot & 15;    // row n, 8-elem chunk k16
        const float* wp = W + (size_t)n * D_IN + k16 * 8;
        float4 w0 = *(const float4*)wp;
        float4 w1 = *(const float4*)(wp + 4);
        union { unsigned int u[4]; short8 s; } ua;
        ua.u[0] = pk2bf(w0.x, w0.y); ua.u[1] = pk2bf(w0.z, w0.w);
        ua.u[2] = pk2bf(w1.x, w1.y); ua.u[3] = pk2bf(w1.z, w1.w);
        int idx = n * D_IN + ((k16 * 8) ^ ((n & 7) << 3));
        *(short8*)&Wl[idx] = ua.s;
    }
    __syncthreads();

    const int wid = t >> 6, l = t & 63;
    const int r16 = l & 15, kq = l >> 4;       // kq in 0..3
    const int node0 = blockIdx.x * 64 + wid * 16;
    int arow = node0 + r16;
    if (arow >= N_NODES) arow = N_NODES - 1;   // clamp; stores guarded below
    const float* fp = feat + (size_t)arow * D_IN + kq * 8;

    f32x4 acc[16];
#pragma unroll
    for (int i = 0; i < 16; ++i) acc[i] = (f32x4){0.f, 0.f, 0.f, 0.f};

#pragma unroll
    for (int kc = 0; kc < 4; ++kc) {
        float4 a0 = *(const float4*)(fp + kc * 32);
        float4 a1 = *(const float4*)(fp + kc * 32 + 4);
        union { unsigned int u[4]; short8 s; } ua;
        ua.u[0] = pk2bf(a0.x, a0.y); ua.u[1] = pk2bf(a0.z, a0.w);
        ua.u[2] = pk2bf(a1.x, a1.y); ua.u[3] = pk2bf(a1.z, a1.w);
        short8 af = ua.s;
#pragma unroll
        for (int nsub = 0; nsub < 16; ++nsub) {
            int n = nsub * 16 + r16;
            int idx = n * D_IN + ((kc * 32 + kq * 8) ^ ((n & 7) << 3));
            short8 bf = *(short8*)&Wl[idx];
            acc[nsub] = __builtin_amdgcn_mfma_f32_16x16x32_bf16(af, bf, acc[nsub], 0, 0, 0);
        }
    }

    // epilogue 1: el/er from fp32 accumulators (head h = nsub>>1)
    const int nodeb = node0 + kq * 4;          // this lane's 4 acc rows
#pragma unroll
    for (int h = 0; h < 8; ++h) {
        float al0 = attn_l[h * 32 + r16],      al1 = attn_l[h * 32 + 16 + r16];
        float ar0 = attn_r[h * 32 + r16],      ar1 = attn_r[h * 32 + 16 + r16];
        float ev[4], rv[4];
#pragma unroll
        for (int g = 0; g < 4; ++g) {
            ev[g] = acc[2 * h][g] * al0 + acc[2 * h + 1][g] * al1;
            rv[g] = acc[2 * h][g] * ar0 + acc[2 * h + 1][g] * ar1;
        }
#pragma unroll
        for (int g = 0; g < 4; ++g) {
            ev[g] += __shfl_xor(ev[g], 1); ev[g] += __shfl_xor(ev[g], 2);
            ev[g] += __shfl_xor(ev[g], 4); ev[g] += __shfl_xor(ev[g], 8);
            rv[g] += __shfl_xor(rv[g], 1); rv[g] += __shfl_xor(rv[g], 2);
            rv[g] += __shfl_xor(rv[g], 4); rv[g] += __shfl_xor(rv[g], 8);
        }
        if (r16 == 0) {
#pragma unroll
            for (int g = 0; g < 4; ++g) {
                int nd = nodeb + g;
                if (nd < N_NODES) {
                    el[nd * 8 + h] = ev[g];
                    er[nd * 8 + h] = rv[g];
                }
            }
        }
    }
    // epilogue 2: fs bf16 stores
#pragma unroll
    for (int nsub = 0; nsub < 16; ++nsub) {
        int col = nsub * 16 + r16;
#pragma unroll
        for (int g = 0; g < 4; ++g) {
            int nd = nodeb + g;
            if (nd < N_NODES) fsb[(size_t)nd * HF + col] = f2bf(acc[nsub][g]);
        }
    }
}

// ---------------------------------------------------------------------------
// Kernel 4: CSR row offsets from sorted dst
// ---------------------------------------------------------------------------
__global__ __launch_bounds__(256) void build_offsets(const int* __restrict__ dst,
                                                     int* __restrict__ off) {
    int n = blockIdx.x * blockDim.x + threadIdx.x;
    if (n > N_NODES) return;
    int lo = 0, hi = E_EDGES;
    while (lo < hi) {
        int mid = (lo + hi) >> 1;
        if (dst[mid] < n) lo = mid + 1; else hi = mid;
    }
    off[n] = lo;
}

// ---------------------------------------------------------------------------
// Kernel 5: per-edge p = exp(leakyrelu(w*(el+er+escore+tscore))), bf16 out.
// ---------------------------------------------------------------------------
__global__ __launch_bounds__(256) void edge_kernel(const float* __restrict__ ee,
        const int* __restrict__ src, const int* __restrict__ dst,
        const int* __restrict__ etype, const float* __restrict__ el,
        const float* __restrict__ er, const float* __restrict__ M,
        const float* __restrict__ ttab, const float* __restrict__ w,
        unsigned short* __restrict__ pexp) {
    __shared__ float sM[64], sT[64], sw[8];
    int t = threadIdx.x;
    if (t < 64) { sM[t] = M[t]; sT[t] = ttab[t]; }
    if (t < 8) sw[t] = w[t];
    __syncthreads();
    int e = blockIdx.x * 256 + t;
    if (e >= E_EDGES) return;
    int s = src[e], d = dst[e], ty = etype[e];
    float4 e0 = *(const float4*)&ee[(size_t)e * 8];
    float4 e1 = *(const float4*)&ee[(size_t)e * 8 + 4];
    float4 l0 = *(const float4*)&el[s * 8];
    float4 l1 = *(const float4*)&el[s * 8 + 4];
    float4 r0 = *(const float4*)&er[d * 8];
    float4 r1 = *(const float4*)&er[d * 8 + 4];
    float wt = sw[ty];
    float lv[8] = {l0.x,l0.y,l0.z,l0.w,l1.x,l1.y,l1.z,l1.w};
    float rv[8] = {r0.x,r0.y,r0.z,r0.w,r1.x,r1.y,r1.z,r1.w};
    unsigned int o[4];
#pragma unroll
    for (int hp = 0; hp < 4; ++hp) {
        float p2[2];
#pragma unroll
        for (int i = 0; i < 2; ++i) {
            int h = hp * 2 + i;
            float sc = lv[h] + rv[h] + sT[ty * 8 + h];
            sc += e0.x*sM[h*8+0] + e0.y*sM[h*8+1] + e0.z*sM[h*8+2] + e0.w*sM[h*8+3]
                + e1.x*sM[h*8+4] + e1.y*sM[h*8+5] + e1.z*sM[h*8+6] + e1.w*sM[h*8+7];
            sc *= wt;
            sc = (sc >= 0.f) ? sc : NEG_SLOPE * sc;
            p2[i] = __expf(sc);
        }
        o[hp] = (unsigned int)f2bf(p2[0]) | ((unsigned int)f2bf(p2[1]) << 16);
    }
    *(uint4*)&pexp[(size_t)e * 8] = make_uint4(o[0], o[1], o[2], o[3]);
}

// ---------------------------------------------------------------------------
// Kernel 6: single-pass softmax-normalized aggregation. One wave per dst node.
//   Latency fix: cooperative src prefetch (src[base+l] -> shfl) removes the
//   src load from the dependent chain; 4x unroll puts 4 fs-row gathers +
//   4 pexp loads in flight per round.
// ---------------------------------------------------------------------------
__global__ __launch_bounds__(256) void agg_kernel(const unsigned short* __restrict__ pexp,
        const unsigned short* __restrict__ fsb, const int* __restrict__ src,
        const int* __restrict__ off, const float* __restrict__ bias,
        float* __restrict__ out) {
    const int wid = threadIdx.x >> 6;
    const int l = threadIdx.x & 63;
    const int n = blockIdx.x * 4 + wid;
    if (n >= N_NODES) return;
    const int beg = off[n], end = off[n + 1];
    const int c0 = 4 * l;
    const int h = l >> 3;
    const float4 b4 = *(const float4*)&bias[c0];
    float* op = &out[(size_t)n * HF + c0];
    if (beg == end) { *(float4*)op = b4; return; }
    float a0 = 0.f, a1 = 0.f, a2 = 0.f, a3 = 0.f, z = 0.f;
    for (int base = beg; base < end; base += 64) {
        const int remn = end - base;
        const int rem = remn < 64 ? remn : 64;
        int idx = base + l; if (idx >= end) idx = end - 1;
        const int sl = src[idx];                 // one coalesced read / chunk
        int j = 0;
        for (; j + 4 <= rem; j += 4) {
            const int s0 = __shfl(sl, j);
            const int s1 = __shfl(sl, j + 1);
            const int s2 = __shfl(sl, j + 2);
            const int s3 = __shfl(sl, j + 3);
            const float p0 = bf2f(pexp[(size_t)(base + j) * 8 + h]);
            const float p1 = bf2f(pexp[(size_t)(base + j + 1) * 8 + h]);
            const float p2 = bf2f(pexp[(size_t)(base + j + 2) * 8 + h]);
            const float p3 = bf2f(pexp[(size_t)(base + j + 3) * 8 + h]);
            const ushort4 f0 = *(const ushort4*)&fsb[(size_t)s0 * HF + c0];
            const ushort4 f1 = *(const ushort4*)&fsb[(size_t)s1 * HF + c0];
            const ushort4 f2 = *(const ushort4*)&fsb[(size_t)s2 * HF + c0];
            const ushort4 f3 = *(const ushort4*)&fsb[(size_t)s3 * HF + c0];
            a0 += p0 * bf2f(f0.x); a1 += p0 * bf2f(f0.y);
            a2 += p0 * bf2f(f0.z); a3 += p0 * bf2f(f0.w); z += p0;
            a0 += p1 * bf2f(f1.x); a1 += p1 * bf2f(f1.y);
            a2 += p1 * bf2f(f1.z); a3 += p1 * bf2f(f1.w); z += p1;
            a0 += p2 * bf2f(f2.x); a1 += p2 * bf2f(f2.y);
            a2 += p2 * bf2f(f2.z); a3 += p2 * bf2f(f2.w); z += p2;
            a0 += p3 * bf2f(f3.x); a1 += p3 * bf2f(f3.y);
            a2 += p3 * bf2f(f3.z); a3 += p3 * bf2f(f3.w); z += p3;
        }
        for (; j < rem; ++j) {
            const int s0 = __shfl(sl, j);
            const float p0 = bf2f(pexp[(size_t)(base + j) * 8 + h]);
            const ushort4 f0 = *(const ushort4*)&fsb[(size_t)s0 * HF + c0];
            a0 += p0 * bf2f(f0.x); a1 += p0 * bf2f(f0.y);
            a2 += p0 * bf2f(f0.z); a3 += p0 * bf2f(f0.w); z += p0;
        }
    }
    const float rz = 1.f / z;
    *(float4*)op = make_float4(a0 * rz + b4.x, a1 * rz + b4.y,
                               a2 * rz + b4.z, a3 * rz + b4.w);
}

// ---------------------------------------------------------------------------
extern "C" void kernel_launch(void* const* d_in, const int* in_sizes, int n_in,
                              void* d_out, int out_size, void* d_ws, size_t ws_size,
                              hipStream_t stream) {
    const float* feat     = (const float*)d_in[0];
    const float* ee       = (const float*)d_in[1];
    const int*   src      = (const int*)d_in[2];
    const int*   dst      = (const int*)d_in[3];
    const int*   etype    = (const int*)d_in[4];
    const float* W_src    = (const float*)d_in[5];
    const float* attn_l   = (const float*)d_in[6];
    const float* attn_r   = (const float*)d_in[7];
    const float* attn_e   = (const float*)d_in[8];
    const float* W_e      = (const float*)d_in[9];
    const float* type_emb = (const float*)d_in[10];
    const float* W_et     = (const float*)d_in[11];
    const float* attn_et  = (const float*)d_in[12];
    const float* bias     = (const float*)d_in[13];
    float* out = (float*)d_out;

    char* ws = (char*)d_ws;
    size_t o = 0;
    auto alloc = [&](size_t bytes) -> void* {
        void* p = ws + o;
        o = (o + bytes + 255) & ~(size_t)255;
        return p;
    };
    unsigned short* fsb  = (unsigned short*)alloc((size_t)N_NODES * HF * 2); // 25.6 MB
    unsigned short* pexp = (unsigned short*)alloc((size_t)E_EDGES * 8 * 2);  // 12.8 MB
    float* el    = (float*)alloc((size_t)N_NODES * 8 * 4);
    float* er    = (float*)alloc((size_t)N_NODES * 8 * 4);
    int*   off   = (int*)alloc((size_t)(N_NODES + 1) * 4);
    int*   partials = (int*)alloc((size_t)HIST_BLOCKS * 8 * 4);
    float* M     = (float*)alloc(64 * 4);
    float* ttab  = (float*)alloc(64 * 4);
    float* w     = (float*)alloc(T_TYPES * 4);

    hist_part<<<HIST_BLOCKS, 256, 0, stream>>>(etype, partials);
    tables_kernel<<<1, 256, 0, stream>>>(attn_e, W_e, attn_et, W_et, type_emb,
                                         partials, M, ttab, w);
    node_gemm<<<(N_NODES + 63) / 64, 256, 0, stream>>>(feat, W_src, attn_l, attn_r,
                                                       fsb, el, er);
    build_offsets<<<(N_NODES + 1 + 255) / 256, 256, 0, stream>>>(dst, off);
    edge_kernel<<<(E_EDGES + 255) / 256, 256, 0, stream>>>(
        ee, src, dst, etype, el, er, M, ttab, w, pexp);
    agg_kernel<<<(N_NODES + 3) / 4, 256, 0, stream>>>(pexp, fsb, src, off, bias, out);
}